// Round 3
// baseline (144.338 us; speedup 1.0000x reference)
//
#include <hip/hip_runtime.h>
#include <hip/hip_bf16.h>

// Chamfer loss: preds/gts [8, 3, 8192] fp32 -> scalar fp32.
// Phase 1: per-query min squared distance (both directions), split over refs.
//   Inner loop: process 2 refs/iter -> 3 fma each + one v_max3_f32 merging
//   both into the running max (min(ry-2dot) == -2*max(dot-0.5*ry)).
//   3.5 VALU ops per pair.
// Phase 2: min over ref-splits, sum-reduce, double atomic accumulate.
// Phase 3: convert double -> float output.

#define CN 8192
#define BQ 2048        // queries per block
#define IPT 8          // queries per thread (256 threads * 8)
#define SPLITS 8       // ref-range splits per (dir,batch,qchunk)
#define RB (CN / SPLITS)   // 1024 refs per block
#define TILE 512       // refs staged in LDS per iteration
#define NBATCH 8
#define QCHUNKS (CN / BQ)  // 4

__global__ __launch_bounds__(256) void chamfer_partial(
    const float* __restrict__ preds, const float* __restrict__ gts,
    float* __restrict__ partial) {
  const int bid = blockIdx.x;            // 512 blocks total
  const int s     = bid & (SPLITS - 1);
  const int qc    = (bid >> 3) & (QCHUNKS - 1);
  const int batch = (bid >> 5) & (NBATCH - 1);
  const int dir   = bid >> 8;            // 0: queries=preds, 1: queries=gts

  const float* __restrict__ Qb = (dir ? gts : preds) + batch * 3 * CN;
  const float* __restrict__ Rb = (dir ? preds : gts) + batch * 3 * CN;

  const int tid = threadIdx.x;

  // Load this thread's 8 query points (coalesced: stride-256 within chunk).
  float x0[IPT], x1[IPT], x2[IPT], mm[IPT];
#pragma unroll
  for (int k = 0; k < IPT; ++k) {
    const int q = qc * BQ + k * 256 + tid;
    x0[k] = Qb[q];
    x1[k] = Qb[CN + q];
    x2[k] = Qb[2 * CN + q];
    mm[k] = -INFINITY;   // tracks max_j (dot - 0.5*ry)
  }

  __shared__ float4 ytile[TILE];   // (y0, y1, y2, -0.5*|y|^2)
  const int rbase = s * RB;

  for (int t0i = 0; t0i < RB; t0i += TILE) {
    __syncthreads();
#pragma unroll
    for (int k = 0; k < TILE / 256; ++k) {
      const int r = rbase + t0i + k * 256 + tid;
      const float y0 = Rb[r];
      const float y1 = Rb[CN + r];
      const float y2 = Rb[2 * CN + r];
      ytile[k * 256 + tid] = make_float4(
          y0, y1, y2, -0.5f * fmaf(y0, y0, fmaf(y1, y1, y2 * y2)));
    }
    __syncthreads();

#pragma unroll 2
    for (int j = 0; j < TILE; j += 2) {
      const float4 ya = ytile[j];       // broadcast reads, conflict-free
      const float4 yb = ytile[j + 1];
#pragma unroll
      for (int k = 0; k < IPT; ++k) {
        const float ta =
            fmaf(x2[k], ya.z, fmaf(x1[k], ya.y, fmaf(x0[k], ya.x, ya.w)));
        const float tb =
            fmaf(x2[k], yb.z, fmaf(x1[k], yb.y, fmaf(x0[k], yb.x, yb.w)));
        mm[k] = fmaxf(fmaxf(mm[k], ta), tb);   // -> v_max3_f32
      }
    }
  }

  // Write per-query partial mins: rx + min_j(ry - 2dot) = rx - 2*max_t.
  float* __restrict__ P =
      partial +
      (size_t)(((dir * NBATCH + batch) * QCHUNKS + qc) * SPLITS + s) * BQ;
#pragma unroll
  for (int k = 0; k < IPT; ++k) {
    const float rx = fmaf(x0[k], x0[k], fmaf(x1[k], x1[k], x2[k] * x2[k]));
    P[k * 256 + tid] = fmaf(mm[k], -2.0f, rx);
  }
}

__global__ __launch_bounds__(256) void chamfer_reduce(
    const float* __restrict__ partial, double* __restrict__ acc) {
  const int tid = threadIdx.x;
  const int g = blockIdx.x * 256 + tid;   // 131072 queries total
  const int qlocal = g & (BQ - 1);
  const int grp = g >> 11;                // (dir*8+batch)*QCHUNKS+qc, 0..63

  const float* __restrict__ P = partial + (size_t)grp * (SPLITS * BQ) + qlocal;
  float m = P[0];
#pragma unroll
  for (int s2 = 1; s2 < SPLITS; ++s2) m = fminf(m, P[s2 * BQ]);

  // Block sum: wave64 shuffle reduce, then cross-wave via LDS.
  float v = m;
#pragma unroll
  for (int off = 32; off > 0; off >>= 1) v += __shfl_down(v, off, 64);

  __shared__ float wsum[4];
  if ((tid & 63) == 0) wsum[tid >> 6] = v;
  __syncthreads();
  if (tid == 0) {
    const float b = wsum[0] + wsum[1] + wsum[2] + wsum[3];
    atomicAdd(acc, (double)b);
  }
}

__global__ void chamfer_finalize(const double* __restrict__ acc,
                                 float* __restrict__ out) {
  out[0] = (float)acc[0];
}

extern "C" void kernel_launch(void* const* d_in, const int* in_sizes, int n_in,
                              void* d_out, int out_size, void* d_ws, size_t ws_size,
                              hipStream_t stream) {
  const float* preds = (const float*)d_in[0];
  const float* gts   = (const float*)d_in[1];

  double* acc      = (double*)d_ws;                       // 8 bytes
  float*  partial  = (float*)((char*)d_ws + 256);         // 4 MB partial mins

  hipMemsetAsync(d_ws, 0, 8, stream);   // zero the double accumulator
  chamfer_partial<<<512, 256, 0, stream>>>(preds, gts, partial);
  chamfer_reduce<<<512, 256, 0, stream>>>(partial, acc);
  chamfer_finalize<<<1, 1, 0, stream>>>(acc, (float*)d_out);
}